// Round 6
// baseline (939.359 us; speedup 1.0000x reference)
//
#include <hip/hip_runtime.h>

// GlobalGOCorOpt for MI355X (gfx950) — round 6: multi-kernel full-occupancy,
// workspace-slimmed (55 MB; round-5's 88 MB may have overrun ws_size).
// B=2, NF=4096, C=256, H=W=64, HW=4096, NUM_ITER=2.
// Per iteration: k_score (scores->mres,signs; f in 2048-halves),
// k_floss (split-K=2 fgrad_loss partials), k_fgrad (finalize fgrad+alpha_num),
// k_sg (sg->alpha_den), k_update (filter step; master f32 filter lives in d_out).
// GEMMs: f16 MFMA 16x16x32, fp32 accum, operands straight from L2 (no LDS).

#define NFILT 4096
#define CDIM  256
#define HWDIM 4096

typedef _Float16 f16;
typedef _Float16 f16x8 __attribute__((ext_vector_type(8)));
typedef _Float16 f16x4 __attribute__((ext_vector_type(4)));
typedef float f32x4 __attribute__((ext_vector_type(4)));

// ---------- packed map table {vp*label, vp, sigmoid(mask), 0} ----------
__global__ __launch_bounds__(256) void k_maps(
    const float* __restrict__ wl, const float* __restrict__ wsp,
    const float* __restrict__ wmk, float4* __restrict__ tbl)
{
  int i = blockIdx.x * 256 + threadIdx.x;
  if (i >= 127 * 127) return;
  int yy = i / 127, xx = i - yy * 127;
  float dy = (float)yy - 63.f, dx = (float)xx - 63.f;
  float d2 = 2.f * sqrtf(dy * dy + dx * dx);   // dist / BIN_DISP
  float l = 0.f, v = 0.f, m = 0.f;
#pragma unroll
  for (int k = 0; k < 9; ++k) {
    float t = fmaxf(1.f - fabsf(d2 - (float)k), 0.f);
    l += wl[k] * t; v += wsp[k] * t; m += wmk[k] * t;
  }
  float t9 = fminf(fmaxf(d2 - 8.f, 0.f), 1.f);
  l += wl[9] * t9; v += wsp[9] * t9; m += wmk[9] * t9;
  tbl[i] = make_float4(v * l, v, 1.f / (1.f + expf(-m)), 0.f);
}

// ---------- feat f32 -> f16 [b][c][yx] and transposed [b][yx][c] ----------
__global__ __launch_bounds__(256) void k_convert(
    const float* __restrict__ feat, f16* __restrict__ featc,
    f16* __restrict__ featT)
{
  __shared__ float tbuf[64][65];
  int bid = blockIdx.x;                        // 512 blocks = 2b x 4cb x 64yb
  int b = bid >> 8, cb = (bid >> 6) & 3, yb = bid & 63;
  int ty = threadIdx.x & 63, tc = threadIdx.x >> 6;
  const float* src = feat + ((size_t)b * CDIM + cb * 64) * HWDIM + yb * 64;
#pragma unroll
  for (int s = 0; s < 16; ++s) {
    int c = s * 4 + tc;
    float v = src[(size_t)c * HWDIM + ty];
    tbuf[c][ty] = v;
    featc[((size_t)b * CDIM + cb * 64 + c) * HWDIM + yb * 64 + ty] = (f16)v;
  }
  __syncthreads();
#pragma unroll
  for (int s = 0; s < 16; ++s) {
    int y = s * 4 + tc;
    featT[((size_t)b * HWDIM + yb * 64 + y) * CDIM + cb * 64 + ty] = (f16)tbuf[ty][y];
  }
}

// ---------- filter_map f32 -> master f32 copy (in d_out) + f16 ----------
__global__ __launch_bounds__(256) void k_filt16(
    const float* __restrict__ src, float* __restrict__ dst32,
    f16* __restrict__ dst16)
{
  const int i = blockIdx.x * 256 + threadIdx.x;       // float4 index
  const float4 v = ((const float4*)src)[i];
  ((float4*)dst32)[i] = v;
  f16x4 h; h[0] = (f16)v.x; h[1] = (f16)v.y; h[2] = (f16)v.z; h[3] = (f16)v.w;
  *(f16x4*)&dst16[(size_t)i * 4] = h;
}

// ---------- K1: scores GEMM + mres epilogue (per batch, per 2048-f half) ----
// grid (32,16), 256 thr. Tile 64f x 256yx; wave w = 64-yx slice.
__global__ __launch_bounds__(256, 3) void k_score(
    const f16* __restrict__ filt16, const f16* __restrict__ featT,
    const float4* __restrict__ tbl, f16* __restrict__ mres,   // [2048][HW] local
    unsigned long long* __restrict__ sgn, int b, int fbase)
{
  const int tid = threadIdx.x, w = tid >> 6, lane = tid & 63;
  const int llo = lane & 15, lhi = lane >> 4;
  const int fb = fbase + blockIdx.x * 64, yx0 = blockIdx.y * 256 + w * 64;
  const f16* A  = filt16 + ((size_t)b * NFILT + fb) * CDIM;
  const f16* Bp = featT  + ((size_t)b * HWDIM + yx0) * CDIM;

  f32x4 acc[4][4] = {};
#pragma unroll
  for (int kk = 0; kk < 8; ++kk) {
    const int ko = kk * 32 + lhi * 8;
    f16x8 a[4], bb[4];
#pragma unroll
    for (int mi = 0; mi < 4; ++mi) a[mi]  = *(const f16x8*)&A [(mi * 16 + llo) * CDIM + ko];
#pragma unroll
    for (int ni = 0; ni < 4; ++ni) bb[ni] = *(const f16x8*)&Bp[(ni * 16 + llo) * CDIM + ko];
#pragma unroll
    for (int mi = 0; mi < 4; ++mi)
#pragma unroll
      for (int ni = 0; ni < 4; ++ni)
        acc[mi][ni] = __builtin_amdgcn_mfma_f32_16x16x32_f16(a[mi], bb[ni], acc[mi][ni], 0, 0, 0);
  }

  unsigned long long sbits = 0ull;
#pragma unroll
  for (int mi = 0; mi < 4; ++mi)
#pragma unroll
    for (int ni = 0; ni < 4; ++ni)
#pragma unroll
      for (int r = 0; r < 4; ++r) {
        const int f  = fb + mi * 16 + lhi * 4 + r;
        const int yx = yx0 + ni * 16 + llo;
        const int y = yx >> 6, x = yx & 63;
        const int t = (63 - (f >> 6) + y) * 127 + (63 - (f & 63) + x);
        const float4 tv = tbl[t];
        const float s  = acc[mi][ni][r];
        const float q  = 0.5f * tv.y;            // 0.5*vp
        const float qa = q * tv.z;               // 0.5*vp*a
        const float h1 = q - qa, h2 = q + qa;
        const float sg0 = (s > 0.f) ? 1.f : ((s < 0.f) ? -1.f : 0.f);
        const float act = h1 * fabsf(s) + h2 * s;
        const float dct = h1 * sg0 + h2;
        mres[(size_t)(f - fbase) * HWDIM + yx] = (f16)(dct * (act - tv.x));
        sbits |= (unsigned long long)(s > 0.f ? 1 : 0) << ((mi * 4 + ni) * 4 + r);
      }
  const int gfb = (fbase >> 6) + blockIdx.x;            // global 64-f block
  const size_t gb = ((size_t)b * 64 + gfb) * 16 + blockIdx.y;
  sgn[(gb * 4 + w) * 64 + lane] = sbits;
}

// ---------- K2: fgrad_loss split-K partials (per batch, per 2048-f half) ----
// grid (64,2), 256 thr. Tile 32f x 256c, K-slice 2048 yx; wave w = 64-c slice.
__global__ __launch_bounds__(256, 4) void k_floss(
    const f16* __restrict__ mres, const f16* __restrict__ featc,
    float* __restrict__ fpart, int b, int fbase)
{
  const int tid = threadIdx.x, w = tid >> 6, lane = tid & 63;
  const int llo = lane & 15, lhi = lane >> 4;
  const int fbl = blockIdx.x * 32, ks = blockIdx.y * 2048;
  const f16* A  = mres  + (size_t)fbl * HWDIM;
  const f16* Bp = featc + ((size_t)b * CDIM + w * 64) * HWDIM;

  f32x4 acc[2][4] = {};
#pragma unroll 4
  for (int kk = 0; kk < 64; ++kk) {
    const int ko = ks + kk * 32 + lhi * 8;
    f16x8 a[2], bb[4];
#pragma unroll
    for (int mi = 0; mi < 2; ++mi) a[mi]  = *(const f16x8*)&A [(size_t)(mi * 16 + llo) * HWDIM + ko];
#pragma unroll
    for (int ni = 0; ni < 4; ++ni) bb[ni] = *(const f16x8*)&Bp[(size_t)(ni * 16 + llo) * HWDIM + ko];
#pragma unroll
    for (int mi = 0; mi < 2; ++mi)
#pragma unroll
      for (int ni = 0; ni < 4; ++ni)
        acc[mi][ni] = __builtin_amdgcn_mfma_f32_16x16x32_f16(a[mi], bb[ni], acc[mi][ni], 0, 0, 0);
  }
  float* out = fpart + (size_t)blockIdx.y * NFILT * CDIM;
#pragma unroll
  for (int mi = 0; mi < 2; ++mi)
#pragma unroll
    for (int ni = 0; ni < 4; ++ni)
#pragma unroll
      for (int r = 0; r < 4; ++r) {
        const int f = fbase + fbl + mi * 16 + lhi * 4 + r;
        const int c = w * 64 + ni * 16 + llo;
        out[(size_t)f * CDIM + c] = acc[mi][ni][r];
      }
}

// ---------- K2b: fgrad = rw*filt + sum(partials); alpha_num; aden=0 ----------
// grid (1024), 256 thr; wave w handles filter f = blk*4 + w, lane covers 4 c.
__global__ __launch_bounds__(256) void k_fgrad(
    const float* __restrict__ fpart, const float* __restrict__ filt32,
    const float* __restrict__ freg,
    float* __restrict__ fgrad32, f16* __restrict__ fgrad16,
    float* __restrict__ anum, float* __restrict__ aden, int b)
{
  const int tid = threadIdx.x, w = tid >> 6, lane = tid & 63;
  const int f = blockIdx.x * 4 + w;
  const float fr = freg[0];
  const float rw = fmaxf(fr * fr, 1e-10f);
  const float4* P  = (const float4*)fpart;
  const size_t row4 = (size_t)f * 64 + lane;
  float4 s0 = P[row4];
  float4 s1 = P[(size_t)1 * NFILT * 64 + row4];
  const float4 fv = ((const float4*)(filt32 + (size_t)b * NFILT * CDIM))[row4];
  float4 fg;
  fg.x = rw * fv.x + s0.x + s1.x;
  fg.y = rw * fv.y + s0.y + s1.y;
  fg.z = rw * fv.z + s0.z + s1.z;
  fg.w = rw * fv.w + s0.w + s1.w;
  ((float4*)(fgrad32 + (size_t)b * NFILT * CDIM))[row4] = fg;
  f16x4 h; h[0] = (f16)fg.x; h[1] = (f16)fg.y; h[2] = (f16)fg.z; h[3] = (f16)fg.w;
  *(f16x4*)&fgrad16[((size_t)b * NFILT * CDIM) + row4 * 4] = h;
  float ss = fg.x * fg.x + fg.y * fg.y + fg.z * fg.z + fg.w * fg.w;
  ss += __shfl_xor(ss, 1);  ss += __shfl_xor(ss, 2);  ss += __shfl_xor(ss, 4);
  ss += __shfl_xor(ss, 8);  ss += __shfl_xor(ss, 16); ss += __shfl_xor(ss, 32);
  if (lane == 0) {
    anum[b * NFILT + f] = ss;
    aden[b * NFILT + f] = 0.f;
  }
}

// ---------- K3: sg GEMM + den_res^2 reduction (both batches) ----------
// grid (64,16,2), 256 thr — same fragment mapping as k_score.
__global__ __launch_bounds__(256, 3) void k_sg(
    const f16* __restrict__ fgrad16, const f16* __restrict__ featT,
    const float4* __restrict__ tbl, const unsigned long long* __restrict__ sgn,
    float* __restrict__ aden)
{
  const int tid = threadIdx.x, w = tid >> 6, lane = tid & 63;
  const int llo = lane & 15, lhi = lane >> 4;
  const int b = blockIdx.z;
  const int fb = blockIdx.x * 64, yx0 = blockIdx.y * 256 + w * 64;
  const f16* A  = fgrad16 + ((size_t)b * NFILT + fb) * CDIM;
  const f16* Bp = featT   + ((size_t)b * HWDIM + yx0) * CDIM;

  f32x4 acc[4][4] = {};
#pragma unroll
  for (int kk = 0; kk < 8; ++kk) {
    const int ko = kk * 32 + lhi * 8;
    f16x8 a[4], bb[4];
#pragma unroll
    for (int mi = 0; mi < 4; ++mi) a[mi]  = *(const f16x8*)&A [(mi * 16 + llo) * CDIM + ko];
#pragma unroll
    for (int ni = 0; ni < 4; ++ni) bb[ni] = *(const f16x8*)&Bp[(ni * 16 + llo) * CDIM + ko];
#pragma unroll
    for (int mi = 0; mi < 4; ++mi)
#pragma unroll
      for (int ni = 0; ni < 4; ++ni)
        acc[mi][ni] = __builtin_amdgcn_mfma_f32_16x16x32_f16(a[mi], bb[ni], acc[mi][ni], 0, 0, 0);
  }

  const size_t gb = ((size_t)b * 64 + blockIdx.x) * 16 + blockIdx.y;
  const unsigned long long sbits = sgn[(gb * 4 + w) * 64 + lane];
  float dacc[4][4] = {};                      // [mi][r]
#pragma unroll
  for (int mi = 0; mi < 4; ++mi)
#pragma unroll
    for (int ni = 0; ni < 4; ++ni)
#pragma unroll
      for (int r = 0; r < 4; ++r) {
        const int f  = fb + mi * 16 + lhi * 4 + r;
        const int yx = yx0 + ni * 16 + llo;
        const int y = yx >> 6, x = yx & 63;
        const int t = (63 - (f >> 6) + y) * 127 + (63 - (f & 63) + x);
        const float4 tv = tbl[t];
        const float q  = 0.5f * tv.y;
        const float qa = q * tv.z;
        const float h1 = q - qa, h2 = q + qa;
        const float sg0 = ((sbits >> ((mi * 4 + ni) * 4 + r)) & 1ull) ? 1.f : -1.f;
        const float dct = h1 * sg0 + h2;
        const float dr  = dct * acc[mi][ni][r];
        dacc[mi][r] += dr * dr;
      }
#pragma unroll
  for (int mi = 0; mi < 4; ++mi)
#pragma unroll
    for (int r = 0; r < 4; ++r) {
      float v = dacc[mi][r];
      v += __shfl_xor(v, 1); v += __shfl_xor(v, 2);
      v += __shfl_xor(v, 4); v += __shfl_xor(v, 8);
      if (llo == 0)
        atomicAdd(&aden[b * NFILT + fb + mi * 16 + lhi * 4 + r], v);
    }
}

// ---------- K4: filter update (master in d_out, in-place) ----------
// grid (2048), 256 thr, float4 per thread over [B][NF][C].
__global__ __launch_bounds__(256) void k_update(
    const float* __restrict__ filtin, const float* __restrict__ fgrad32,
    const float* __restrict__ anum, const float* __restrict__ aden,
    const float* __restrict__ lsl, const float* __restrict__ freg,
    float* __restrict__ filtout, f16* __restrict__ filt16o)
{
  const int i = blockIdx.x * 256 + threadIdx.x;       // float4 index
  const int bf = i >> 6;
  const float fr = freg[0];
  const float rw = fmaxf(fr * fr, 1e-10f);
  const float sl = expf(lsl[0]);
  const float num = anum[bf], den = aden[bf];
  const float alpha = num / fmaxf(den + rw * num, 1e-8f);   // STEPLEN_REG = 0
  const float st = sl * alpha;
  const float4 fv = ((const float4*)filtin)[i];
  const float4 gv = ((const float4*)fgrad32)[i];
  float4 nv;
  nv.x = fv.x - st * gv.x; nv.y = fv.y - st * gv.y;
  nv.z = fv.z - st * gv.z; nv.w = fv.w - st * gv.w;
  ((float4*)filtout)[i] = nv;
  f16x4 h; h[0] = (f16)nv.x; h[1] = (f16)nv.y; h[2] = (f16)nv.z; h[3] = (f16)nv.w;
  *(f16x4*)&filt16o[(size_t)i * 4] = h;
}

extern "C" void kernel_launch(void* const* d_in, const int* in_sizes, int n_in,
                              void* d_out, int out_size, void* d_ws, size_t ws_size,
                              hipStream_t stream) {
  (void)in_sizes; (void)n_in; (void)out_size; (void)ws_size;
  const float* filt  = (const float*)d_in[0];   // filter_map [2][4096][256]
  const float* rfeat = (const float*)d_in[1];   // reference_feat [1][2][256][64][64]
  const float* wl  = (const float*)d_in[3];
  const float* wsp = (const float*)d_in[4];
  const float* wmk = (const float*)d_in[5];
  const float* lsl = (const float*)d_in[6];
  const float* fre = (const float*)d_in[7];

  char* ws = (char*)d_ws;                             // 54.9 MB total
  float4* tbl    = (float4*)(ws + 0);                 // 258 KB (pad 256K)
  f16* featc     = (f16*)(ws + 262144);               // 4 MB
  f16* featT     = (f16*)(ws + 4456448);              // 4 MB
  f16* filt16    = (f16*)(ws + 8650752);              // 4 MB
  f16* fgrad16   = (f16*)(ws + 12845056);             // 4 MB
  float* fgrad32 = (float*)(ws + 17039360);           // 8 MB
  float* anum    = (float*)(ws + 25427968);           // 32 KB
  float* aden    = (float*)(ws + 25460736);           // 32 KB
  unsigned long long* sgn = (unsigned long long*)(ws + 25493504);  // 4 MB
  f16* mres      = (f16*)(ws + 29687808);             // 16 MB (2048-f half)
  float* fpart   = (float*)(ws + 46465024);           // 8 MB (2 K-slices)
  float* filt32  = (float*)d_out;                     // master f32 (8 MB)
  float* out     = (float*)d_out;

  k_maps<<<64, 256, 0, stream>>>(wl, wsp, wmk, tbl);
  k_convert<<<512, 256, 0, stream>>>(rfeat, featc, featT);
  k_filt16<<<2048, 256, 0, stream>>>(filt, filt32, filt16);

  for (int it = 0; it < 2; ++it) {
    for (int b = 0; b < 2; ++b) {
      for (int half = 0; half < 2; ++half) {
        const int fbase = half * 2048;
        k_score<<<dim3(32, 16), 256, 0, stream>>>(filt16, featT, tbl, mres,
                                                  sgn, b, fbase);
        k_floss<<<dim3(64, 2), 256, 0, stream>>>(mres, featc, fpart, b, fbase);
      }
      k_fgrad<<<1024, 256, 0, stream>>>(fpart, filt32, fre, fgrad32, fgrad16,
                                        anum, aden, b);
    }
    k_sg<<<dim3(64, 16, 2), 256, 0, stream>>>(fgrad16, featT, tbl, sgn, aden);
    k_update<<<2048, 256, 0, stream>>>(filt32, fgrad32, anum, aden, lsl, fre,
                                       out, filt16);
  }
}

// Round 7
// 483.152 us; speedup vs baseline: 1.9442x; 1.9442x over previous
//
#include <hip/hip_runtime.h>

// GlobalGOCorOpt for MI355X (gfx950) — round 7: m97-style LDS GEMMs.
// B=2, NF=4096, C=256, H=W=64, HW=4096, NUM_ITER=2.
// GEMM kernels use global_load_lds(16B) staging into XOR-swizzled LDS tiles,
// BK=64, 2-barrier K-loop, f16 MFMA 16x16x32 + fp32 accum.
// k_score: scores->mres(f16)+signs (per batch, per 2048-f half)
// k_floss: fgrad_loss split-K=8 partials (f16)
// k_fgrad: fgrad=rw*filt+sum(partials), fgrad16/32, alpha_num
// k_sg:    sg GEMM -> den partials (no atomics)
// k_update: alpha + filter step (master f32 filter lives in d_out)

#define NFILT 4096
#define CDIM  256
#define HWDIM 4096

typedef _Float16 f16;
typedef _Float16 f16x8 __attribute__((ext_vector_type(8)));
typedef _Float16 f16x4 __attribute__((ext_vector_type(4)));
typedef float f32x4 __attribute__((ext_vector_type(4)));

#define MFMA(a, b, c) __builtin_amdgcn_mfma_f32_16x16x32_f16((a), (b), (c), 0, 0, 0)

// Stage an [R rows x 64 f16] tile from g (row stride gstride f16, col offset
// col0) into linear LDS [R][64] via global_load_lds, with the global SOURCE
// pre-swizzled (slot ^= row&7) so that XOR'd ds_reads are bank-balanced.
// Wave w covers rows [w*(R/4), +R/4); each inst = 8 rows (1 KB).
#define STAGE(g, gstride, col0, lds, R)                                         \
  {                                                                             \
    _Pragma("unroll")                                                           \
    for (int i_ = 0; i_ < (R) / 32; ++i_) {                                     \
      const int rbase_ = w * ((R) / 4) + i_ * 8;                                \
      const int row_   = rbase_ + (lane >> 3);                                  \
      const int slot_  = lane & 7;                                              \
      const int col_   = (col0) + ((slot_ ^ (row_ & 7)) << 3);                  \
      __builtin_amdgcn_global_load_lds(                                         \
          (const __attribute__((address_space(1))) void*)                       \
              ((g) + (size_t)row_ * (gstride) + col_),                          \
          (__attribute__((address_space(3))) void*)((lds) + rbase_ * 64),       \
          16, 0, 0);                                                            \
    }                                                                           \
  }

// XOR'd LDS read index for logical (row, 16B-slot)
#define LIDX(row, slot) (((row) * 64) + ((((slot) ^ ((row) & 7))) << 3))

// ---------- packed map table {vp*label, vp, sigmoid(mask), 0} ----------
__global__ __launch_bounds__(256) void k_maps(
    const float* __restrict__ wl, const float* __restrict__ wsp,
    const float* __restrict__ wmk, float4* __restrict__ tbl)
{
  int i = blockIdx.x * 256 + threadIdx.x;
  if (i >= 127 * 127) return;
  int yy = i / 127, xx = i - yy * 127;
  float dy = (float)yy - 63.f, dx = (float)xx - 63.f;
  float d2 = 2.f * sqrtf(dy * dy + dx * dx);   // dist / BIN_DISP
  float l = 0.f, v = 0.f, m = 0.f;
#pragma unroll
  for (int k = 0; k < 9; ++k) {
    float t = fmaxf(1.f - fabsf(d2 - (float)k), 0.f);
    l += wl[k] * t; v += wsp[k] * t; m += wmk[k] * t;
  }
  float t9 = fminf(fmaxf(d2 - 8.f, 0.f), 1.f);
  l += wl[9] * t9; v += wsp[9] * t9; m += wmk[9] * t9;
  tbl[i] = make_float4(v * l, v, 1.f / (1.f + expf(-m)), 0.f);
}

// ---------- feat f32 -> f16 [b][c][yx] and transposed [b][yx][c] ----------
__global__ __launch_bounds__(256) void k_convert(
    const float* __restrict__ feat, f16* __restrict__ featc,
    f16* __restrict__ featT)
{
  __shared__ float tbuf[64][65];
  int bid = blockIdx.x;                        // 512 blocks = 2b x 4cb x 64yb
  int b = bid >> 8, cb = (bid >> 6) & 3, yb = bid & 63;
  int ty = threadIdx.x & 63, tc = threadIdx.x >> 6;
  const float* src = feat + ((size_t)b * CDIM + cb * 64) * HWDIM + yb * 64;
#pragma unroll
  for (int s = 0; s < 16; ++s) {
    int c = s * 4 + tc;
    float v = src[(size_t)c * HWDIM + ty];
    tbuf[c][ty] = v;
    featc[((size_t)b * CDIM + cb * 64 + c) * HWDIM + yb * 64 + ty] = (f16)v;
  }
  __syncthreads();
#pragma unroll
  for (int s = 0; s < 16; ++s) {
    int y = s * 4 + tc;
    featT[((size_t)b * HWDIM + yb * 64 + y) * CDIM + cb * 64 + ty] = (f16)tbuf[ty][y];
  }
}

// ---------- filter_map f32 -> master f32 copy (in d_out) + f16 ----------
__global__ __launch_bounds__(256) void k_filt16(
    const float* __restrict__ src, float* __restrict__ dst32,
    f16* __restrict__ dst16)
{
  const int i = blockIdx.x * 256 + threadIdx.x;       // float4 index
  const float4 v = ((const float4*)src)[i];
  ((float4*)dst32)[i] = v;
  f16x4 h; h[0] = (f16)v.x; h[1] = (f16)v.y; h[2] = (f16)v.z; h[3] = (f16)v.w;
  *(f16x4*)&dst16[(size_t)i * 4] = h;
}

// ---------- K1: scores GEMM + mres epilogue (per batch, per 2048-f half) ----
// grid (16,32), 256 thr. Tile 128f x 128yx, waves 2x2, BK=64, K=256.
__global__ __launch_bounds__(256) void k_score(
    const f16* __restrict__ filt16, const f16* __restrict__ featT,
    const float4* __restrict__ tbl, f16* __restrict__ mres,   // [2048][HW]
    unsigned long long* __restrict__ sgn, int b, int half)
{
  __shared__ f16 As[128 * 64], Bs[128 * 64];
  const int tid = threadIdx.x, w = tid >> 6, lane = tid & 63;
  const int llo = lane & 15, lhi = lane >> 4;
  const int wr = w >> 1, wc = w & 1;
  const int fbase = half * 2048;
  const int fb = blockIdx.x * 128;             // local within half
  const int yxb = blockIdx.y * 128;
  const f16* A  = filt16 + ((size_t)b * NFILT + fbase + fb) * CDIM;
  const f16* Bg = featT  + ((size_t)b * HWDIM + yxb) * CDIM;

  f32x4 acc[4][4] = {};
  for (int ks = 0; ks < 4; ++ks) {
    if (ks) __syncthreads();
    STAGE(A,  CDIM, ks * 64, As, 128);
    STAGE(Bg, CDIM, ks * 64, Bs, 128);
    __syncthreads();
#pragma unroll
    for (int kk = 0; kk < 2; ++kk) {
      f16x8 av[4], bv[4];
#pragma unroll
      for (int mi = 0; mi < 4; ++mi)
        av[mi] = *(const f16x8*)&As[LIDX(wr * 64 + mi * 16 + llo, kk * 4 + lhi)];
#pragma unroll
      for (int ni = 0; ni < 4; ++ni)
        bv[ni] = *(const f16x8*)&Bs[LIDX(wc * 64 + ni * 16 + llo, kk * 4 + lhi)];
#pragma unroll
      for (int mi = 0; mi < 4; ++mi)
#pragma unroll
        for (int ni = 0; ni < 4; ++ni)
          acc[mi][ni] = MFMA(av[mi], bv[ni], acc[mi][ni]);
    }
  }

  unsigned long long sbits = 0ull;
#pragma unroll
  for (int mi = 0; mi < 4; ++mi)
#pragma unroll
    for (int ni = 0; ni < 4; ++ni)
#pragma unroll
      for (int r = 0; r < 4; ++r) {
        const int f_loc = fb + wr * 64 + mi * 16 + lhi * 4 + r;
        const int f  = fbase + f_loc;
        const int yx = yxb + wc * 64 + ni * 16 + llo;
        const int y = yx >> 6, x = yx & 63;
        const int t = (63 - (f >> 6) + y) * 127 + (63 - (f & 63) + x);
        const float4 tv = tbl[t];
        const float s  = acc[mi][ni][r];
        const float q  = 0.5f * tv.y;            // 0.5*vp
        const float qa = q * tv.z;               // 0.5*vp*a
        const float h1 = q - qa, h2 = q + qa;
        const float sg0 = (s > 0.f) ? 1.f : ((s < 0.f) ? -1.f : 0.f);
        const float act = h1 * fabsf(s) + h2 * s;
        const float dct = h1 * sg0 + h2;
        mres[(size_t)f_loc * HWDIM + yx] = (f16)(dct * (act - tv.x));
        sbits |= (unsigned long long)(s > 0.f ? 1 : 0) << ((mi * 4 + ni) * 4 + r);
      }
  sgn[(((size_t)(b * 2 + half) * 16 + blockIdx.x) * 32 + blockIdx.y) * 256 + tid] = sbits;
}

// ---------- K2: fgrad_loss split-K partials (per batch, per 2048-f half) ----
// grid (32,2,8), 256 thr. Tile 64f x 128c, waves 1x4, K-slice 512, BK=64.
__global__ __launch_bounds__(256) void k_floss(
    const f16* __restrict__ mres, const f16* __restrict__ featc,
    f16* __restrict__ fpart, int b)
{
  __shared__ f16 As[64 * 64], Bs[128 * 64];
  const int tid = threadIdx.x, w = tid >> 6, lane = tid & 63;
  const int llo = lane & 15, lhi = lane >> 4;
  const int fbl = blockIdx.x * 64, cb = blockIdx.y * 128, s = blockIdx.z;
  const f16* A  = mres + (size_t)fbl * HWDIM;
  const f16* Bg = featc + ((size_t)b * CDIM + cb) * HWDIM;

  f32x4 acc[4][2] = {};
  for (int ks = 0; ks < 8; ++ks) {
    if (ks) __syncthreads();
    STAGE(A,  HWDIM, s * 512 + ks * 64, As, 64);
    STAGE(Bg, HWDIM, s * 512 + ks * 64, Bs, 128);
    __syncthreads();
#pragma unroll
    for (int kk = 0; kk < 2; ++kk) {
      f16x8 av[4], bv[2];
#pragma unroll
      for (int mi = 0; mi < 4; ++mi)
        av[mi] = *(const f16x8*)&As[LIDX(mi * 16 + llo, kk * 4 + lhi)];
#pragma unroll
      for (int ni = 0; ni < 2; ++ni)
        bv[ni] = *(const f16x8*)&Bs[LIDX(w * 32 + ni * 16 + llo, kk * 4 + lhi)];
#pragma unroll
      for (int mi = 0; mi < 4; ++mi)
#pragma unroll
        for (int ni = 0; ni < 2; ++ni)
          acc[mi][ni] = MFMA(av[mi], bv[ni], acc[mi][ni]);
    }
  }
#pragma unroll
  for (int mi = 0; mi < 4; ++mi)
#pragma unroll
    for (int ni = 0; ni < 2; ++ni)
#pragma unroll
      for (int r = 0; r < 4; ++r) {
        const int f = fbl + mi * 16 + lhi * 4 + r;           // local in half
        const int c = cb + w * 32 + ni * 16 + llo;
        fpart[((size_t)s * 2048 + f) * CDIM + c] = (f16)acc[mi][ni][r];
      }
}

// ---------- K2b: fgrad = rw*filt + sum(partials); alpha_num ----------
// grid 512, 256 thr: wave w owns f_loc = blk*4 + w; lane covers 4 c.
__global__ __launch_bounds__(256) void k_fgrad(
    const f16* __restrict__ fpart, const float* __restrict__ filt32,
    const float* __restrict__ freg,
    float* __restrict__ fgrad32, f16* __restrict__ fgrad16,
    float* __restrict__ anum, int b, int half)
{
  const int tid = threadIdx.x, w = tid >> 6, lane = tid & 63;
  const int f_loc = blockIdx.x * 4 + w;                // 0..2047
  const int f = half * 2048 + f_loc;                   // 0..4095
  const float fr = freg[0];
  const float rw = fmaxf(fr * fr, 1e-10f);
  float4 sum = make_float4(0.f, 0.f, 0.f, 0.f);
#pragma unroll
  for (int s = 0; s < 8; ++s) {
    f16x4 p = *(const f16x4*)&fpart[((size_t)s * 2048 + f_loc) * CDIM + lane * 4];
    sum.x += (float)p[0]; sum.y += (float)p[1];
    sum.z += (float)p[2]; sum.w += (float)p[3];
  }
  const float4 fv = ((const float4*)(filt32 + ((size_t)b * NFILT + f) * CDIM))[lane];
  float4 fg;
  fg.x = rw * fv.x + sum.x; fg.y = rw * fv.y + sum.y;
  fg.z = rw * fv.z + sum.z; fg.w = rw * fv.w + sum.w;
  ((float4*)(fgrad32 + (size_t)f * CDIM))[lane] = fg;
  f16x4 h; h[0] = (f16)fg.x; h[1] = (f16)fg.y; h[2] = (f16)fg.z; h[3] = (f16)fg.w;
  *(f16x4*)&fgrad16[(size_t)f * CDIM + lane * 4] = h;
  float ss = fg.x * fg.x + fg.y * fg.y + fg.z * fg.z + fg.w * fg.w;
  ss += __shfl_xor(ss, 1);  ss += __shfl_xor(ss, 2);  ss += __shfl_xor(ss, 4);
  ss += __shfl_xor(ss, 8);  ss += __shfl_xor(ss, 16); ss += __shfl_xor(ss, 32);
  if (lane == 0) anum[b * NFILT + f] = ss;
}

// ---------- K3: sg GEMM + den_res^2 partials (per batch) ----------
// grid (32,32), 256 thr. Same tile geometry as k_score; full 4096 f.
__global__ __launch_bounds__(256) void k_sg(
    const f16* __restrict__ fgrad16, const f16* __restrict__ featT,
    const float4* __restrict__ tbl, const unsigned long long* __restrict__ sgn,
    float* __restrict__ denp, int b)                   // denp[64][4096]
{
  __shared__ f16 As[128 * 64], Bs[128 * 64];
  const int tid = threadIdx.x, w = tid >> 6, lane = tid & 63;
  const int llo = lane & 15, lhi = lane >> 4;
  const int wr = w >> 1, wc = w & 1;
  const int fb = blockIdx.x * 128;                     // 0..4095
  const int yxb = blockIdx.y * 128;
  const f16* A  = fgrad16 + (size_t)fb * CDIM;
  const f16* Bg = featT + ((size_t)b * HWDIM + yxb) * CDIM;

  f32x4 acc[4][4] = {};
  for (int ks = 0; ks < 4; ++ks) {
    if (ks) __syncthreads();
    STAGE(A,  CDIM, ks * 64, As, 128);
    STAGE(Bg, CDIM, ks * 64, Bs, 128);
    __syncthreads();
#pragma unroll
    for (int kk = 0; kk < 2; ++kk) {
      f16x8 av[4], bv[4];
#pragma unroll
      for (int mi = 0; mi < 4; ++mi)
        av[mi] = *(const f16x8*)&As[LIDX(wr * 64 + mi * 16 + llo, kk * 4 + lhi)];
#pragma unroll
      for (int ni = 0; ni < 4; ++ni)
        bv[ni] = *(const f16x8*)&Bs[LIDX(wc * 64 + ni * 16 + llo, kk * 4 + lhi)];
#pragma unroll
      for (int mi = 0; mi < 4; ++mi)
#pragma unroll
        for (int ni = 0; ni < 4; ++ni)
          acc[mi][ni] = MFMA(av[mi], bv[ni], acc[mi][ni]);
    }
  }

  const int half = blockIdx.x >> 4, mbl = blockIdx.x & 15;
  const unsigned long long sbits =
      sgn[(((size_t)(b * 2 + half) * 16 + mbl) * 32 + blockIdx.y) * 256 + tid];
  float dacc[4][4] = {};                               // [mi][r]
#pragma unroll
  for (int mi = 0; mi < 4; ++mi)
#pragma unroll
    for (int ni = 0; ni < 4; ++ni)
#pragma unroll
      for (int r = 0; r < 4; ++r) {
        const int f  = fb + wr * 64 + mi * 16 + lhi * 4 + r;
        const int yx = yxb + wc * 64 + ni * 16 + llo;
        const int y = yx >> 6, x = yx & 63;
        const int t = (63 - (f >> 6) + y) * 127 + (63 - (f & 63) + x);
        const float4 tv = tbl[t];
        const float q  = 0.5f * tv.y;
        const float qa = q * tv.z;
        const float h1 = q - qa, h2 = q + qa;
        const float sg0 = ((sbits >> ((mi * 4 + ni) * 4 + r)) & 1ull) ? 1.f : -1.f;
        const float dct = h1 * sg0 + h2;
        const float dr  = dct * acc[mi][ni][r];
        dacc[mi][r] += dr * dr;
      }
#pragma unroll
  for (int mi = 0; mi < 4; ++mi)
#pragma unroll
    for (int r = 0; r < 4; ++r) {
      float v = dacc[mi][r];
      v += __shfl_xor(v, 1); v += __shfl_xor(v, 2);
      v += __shfl_xor(v, 4); v += __shfl_xor(v, 8);
      if (llo == 0)
        denp[(size_t)(blockIdx.y * 2 + wc) * NFILT + fb + wr * 64 + mi * 16 + lhi * 4 + r] = v;
    }
}

// ---------- K4: alpha + filter update (master in d_out) ----------
// grid 1024, 256 thr; thread i -> f = i>>6, c-quad = i&63.
__global__ __launch_bounds__(256) void k_update(
    float* __restrict__ filt32, const float* __restrict__ fgrad32,
    const float* __restrict__ anum, const float* __restrict__ denp,
    const float* __restrict__ lsl, const float* __restrict__ freg,
    f16* __restrict__ filt16o, int b)
{
  const int i = blockIdx.x * 256 + threadIdx.x;
  const int f = i >> 6, cq = i & 63;
  const float fr = freg[0];
  const float rw = fmaxf(fr * fr, 1e-10f);
  const float sl = expf(lsl[0]);
  float den = 0.f;
#pragma unroll
  for (int j = 0; j < 64; ++j) den += denp[(size_t)j * NFILT + f];
  const float num = anum[b * NFILT + f];
  const float alpha = num / fmaxf(den + rw * num, 1e-8f);   // STEPLEN_REG = 0
  const float st = sl * alpha;
  const size_t row4 = ((size_t)b * NFILT + f) * 64 + cq;
  const float4 fv = ((const float4*)filt32)[row4];
  const float4 gv = ((const float4*)fgrad32)[(size_t)f * 64 + cq];
  float4 nv;
  nv.x = fv.x - st * gv.x; nv.y = fv.y - st * gv.y;
  nv.z = fv.z - st * gv.z; nv.w = fv.w - st * gv.w;
  ((float4*)filt32)[row4] = nv;
  f16x4 h; h[0] = (f16)nv.x; h[1] = (f16)nv.y; h[2] = (f16)nv.z; h[3] = (f16)nv.w;
  *(f16x4*)&filt16o[row4 * 4] = h;
}

extern "C" void kernel_launch(void* const* d_in, const int* in_sizes, int n_in,
                              void* d_out, int out_size, void* d_ws, size_t ws_size,
                              hipStream_t stream) {
  (void)in_sizes; (void)n_in; (void)out_size; (void)ws_size;
  const float* filt  = (const float*)d_in[0];   // filter_map [2][4096][256]
  const float* rfeat = (const float*)d_in[1];   // reference_feat [1][2][256][64][64]
  const float* wl  = (const float*)d_in[3];
  const float* wsp = (const float*)d_in[4];
  const float* wmk = (const float*)d_in[5];
  const float* lsl = (const float*)d_in[6];
  const float* fre = (const float*)d_in[7];

  char* ws = (char*)d_ws;                             // 47.3 MB total
  float4* tbl    = (float4*)(ws + 0);                 // 258 KB (pad 256K)
  f16* featc     = (f16*)(ws + 262144);               // 4 MB
  f16* featT     = (f16*)(ws + 4456448);              // 4 MB
  f16* filt16    = (f16*)(ws + 8650752);              // 4 MB [2][4096][256]
  f16* fgrad16   = (f16*)(ws + 12845056);             // 2 MB (per-batch reuse)
  float* fgrad32 = (float*)(ws + 14942208);           // 4 MB (per-batch reuse)
  float* anum    = (float*)(ws + 19136512);           // 32 KB
  float* denp    = (float*)(ws + 19169280);           // 1 MB [64][4096]
  unsigned long long* sgn = (unsigned long long*)(ws + 20217856);  // 4 MB
  f16* mres      = (f16*)(ws + 24412160);             // 16 MB [2048][4096]
  f16* fpart     = (f16*)(ws + 41189376);             // 8 MB [8][2048][256]
  float* filt32  = (float*)d_out;                     // master f32 (8 MB)

  k_maps<<<64, 256, 0, stream>>>(wl, wsp, wmk, tbl);
  k_convert<<<512, 256, 0, stream>>>(rfeat, featc, featT);
  k_filt16<<<2048, 256, 0, stream>>>(filt, filt32, filt16);

  for (int it = 0; it < 2; ++it) {
    for (int b = 0; b < 2; ++b) {
      for (int half = 0; half < 2; ++half) {
        k_score<<<dim3(16, 32), 256, 0, stream>>>(filt16, featT, tbl, mres,
                                                  sgn, b, half);
        k_floss<<<dim3(32, 2, 8), 256, 0, stream>>>(mres, featc, fpart, b);
        k_fgrad<<<512, 256, 0, stream>>>(fpart, filt32, fre, fgrad32, fgrad16,
                                         anum, b, half);
      }
      k_sg<<<dim3(32, 32), 256, 0, stream>>>(fgrad16, featT, tbl, sgn, denp, b);
      k_update<<<1024, 256, 0, stream>>>(filt32, fgrad32, anum, denp, lsl, fre,
                                         filt16, b);
    }
  }
}

// Round 8
// 379.326 us; speedup vs baseline: 2.4764x; 1.2737x over previous
//
#include <hip/hip_runtime.h>

// GlobalGOCorOpt for MI355X (gfx950) — round 8.
// ws_size confirmed 256 MB (harness fill) -> no f-half splitting; batch folded
// into blockIdx.z. 13 launches total. GEMMs: global_load_lds(16B) staging,
// XOR-swizzled LDS, BK=64, 2-phase double-buffered K-loop (frags->regs, issue
// next STAGE, MFMA, one sync per step). f16 MFMA 16x16x32, fp32 accum.

#define NFILT 4096
#define CDIM  256
#define HWDIM 4096

typedef _Float16 f16;
typedef _Float16 f16x8 __attribute__((ext_vector_type(8)));
typedef _Float16 f16x4 __attribute__((ext_vector_type(4)));
typedef float f32x4 __attribute__((ext_vector_type(4)));

#define MFMA(a, b, c) __builtin_amdgcn_mfma_f32_16x16x32_f16((a), (b), (c), 0, 0, 0)

// Stage an [R rows x 64 f16] tile from g (row stride gstride f16, col offset
// col0) into linear LDS [R][64] via global_load_lds, global SOURCE pre-swizzled
// (slot ^= row&7) so XOR'd ds_reads are bank-balanced. Wave w covers rows
// [w*(R/4), +R/4); each inst stages 8 rows (64 lanes x 16B).
#define STAGE(g, gstride, col0, lds, R)                                         \
  {                                                                             \
    _Pragma("unroll")                                                           \
    for (int i_ = 0; i_ < (R) / 32; ++i_) {                                     \
      const int rbase_ = w * ((R) / 4) + i_ * 8;                                \
      const int row_   = rbase_ + (lane >> 3);                                  \
      const int slot_  = lane & 7;                                              \
      const int col_   = (col0) + ((slot_ ^ (row_ & 7)) << 3);                  \
      __builtin_amdgcn_global_load_lds(                                         \
          (const __attribute__((address_space(1))) void*)                       \
              ((g) + (size_t)row_ * (gstride) + col_),                          \
          (__attribute__((address_space(3))) void*)((lds) + rbase_ * 64),       \
          16, 0, 0);                                                            \
    }                                                                           \
  }

// XOR'd LDS read index for logical (row, 16B-slot)
#define LIDX(row, slot) (((row) * 64) + ((((slot) ^ ((row) & 7))) << 3))

// ---------- packed map table {vp*label, vp, sigmoid(mask), 0} ----------
__global__ __launch_bounds__(256) void k_maps(
    const float* __restrict__ wl, const float* __restrict__ wsp,
    const float* __restrict__ wmk, float4* __restrict__ tbl)
{
  int i = blockIdx.x * 256 + threadIdx.x;
  if (i >= 127 * 127) return;
  int yy = i / 127, xx = i - yy * 127;
  float dy = (float)yy - 63.f, dx = (float)xx - 63.f;
  float d2 = 2.f * sqrtf(dy * dy + dx * dx);   // dist / BIN_DISP
  float l = 0.f, v = 0.f, m = 0.f;
#pragma unroll
  for (int k = 0; k < 9; ++k) {
    float t = fmaxf(1.f - fabsf(d2 - (float)k), 0.f);
    l += wl[k] * t; v += wsp[k] * t; m += wmk[k] * t;
  }
  float t9 = fminf(fmaxf(d2 - 8.f, 0.f), 1.f);
  l += wl[9] * t9; v += wsp[9] * t9; m += wmk[9] * t9;
  tbl[i] = make_float4(v * l, v, 1.f / (1.f + expf(-m)), 0.f);
}

// ---------- feat f32 -> f16 [b][c][yx] and transposed [b][yx][c] ----------
__global__ __launch_bounds__(256) void k_convert(
    const float* __restrict__ feat, f16* __restrict__ featc,
    f16* __restrict__ featT)
{
  __shared__ float tbuf[64][65];
  int bid = blockIdx.x;                        // 512 blocks = 2b x 4cb x 64yb
  int b = bid >> 8, cb = (bid >> 6) & 3, yb = bid & 63;
  int ty = threadIdx.x & 63, tc = threadIdx.x >> 6;
  const float* src = feat + ((size_t)b * CDIM + cb * 64) * HWDIM + yb * 64;
#pragma unroll
  for (int s = 0; s < 16; ++s) {
    int c = s * 4 + tc;
    float v = src[(size_t)c * HWDIM + ty];
    tbuf[c][ty] = v;
    featc[((size_t)b * CDIM + cb * 64 + c) * HWDIM + yb * 64 + ty] = (f16)v;
  }
  __syncthreads();
#pragma unroll
  for (int s = 0; s < 16; ++s) {
    int y = s * 4 + tc;
    featT[((size_t)b * HWDIM + yb * 64 + y) * CDIM + cb * 64 + ty] = (f16)tbuf[ty][y];
  }
}

// ---------- filter_map f32 -> master f32 copy (in d_out) + f16 ----------
__global__ __launch_bounds__(256) void k_filt16(
    const float* __restrict__ src, float* __restrict__ dst32,
    f16* __restrict__ dst16)
{
  const int i = blockIdx.x * 256 + threadIdx.x;       // float4 index
  const float4 v = ((const float4*)src)[i];
  ((float4*)dst32)[i] = v;
  f16x4 h; h[0] = (f16)v.x; h[1] = (f16)v.y; h[2] = (f16)v.z; h[3] = (f16)v.w;
  *(f16x4*)&dst16[(size_t)i * 4] = h;
}

// ---------- K1: scores GEMM + mres epilogue ----------
// grid (32,32,2): fb=x*128, yxb=y*128, b=z. Tile 128f x 128yx, waves 2x2,
// BK=64, K=256, 2-phase dbuf.
__global__ __launch_bounds__(256) void k_score(
    const f16* __restrict__ filt16, const f16* __restrict__ featT,
    const float4* __restrict__ tbl, f16* __restrict__ mres,   // [2][4096][HW]
    unsigned long long* __restrict__ sgn)
{
  __shared__ f16 As0[128 * 64], As1[128 * 64], Bs0[128 * 64], Bs1[128 * 64];
  const int tid = threadIdx.x, w = tid >> 6, lane = tid & 63;
  const int llo = lane & 15, lhi = lane >> 4;
  const int wr = w >> 1, wc = w & 1;
  const int b = blockIdx.z;
  const int fb = blockIdx.x * 128, yxb = blockIdx.y * 128;
  const f16* A  = filt16 + ((size_t)b * NFILT + fb) * CDIM;
  const f16* Bg = featT  + ((size_t)b * HWDIM + yxb) * CDIM;

  f32x4 acc[4][4] = {};
  STAGE(A,  CDIM, 0, As0, 128);
  STAGE(Bg, CDIM, 0, Bs0, 128);
  __syncthreads();

  auto kstep = [&](const f16* Ac, const f16* Bc, f16* An, f16* Bn, int coln) {
    f16x8 av[4], bv[4];
#pragma unroll
    for (int mi = 0; mi < 4; ++mi)
      av[mi] = *(const f16x8*)&Ac[LIDX(wr * 64 + mi * 16 + llo, lhi)];
#pragma unroll
    for (int ni = 0; ni < 4; ++ni)
      bv[ni] = *(const f16x8*)&Bc[LIDX(wc * 64 + ni * 16 + llo, lhi)];
    if (An) { STAGE(A, CDIM, coln, An, 128); STAGE(Bg, CDIM, coln, Bn, 128); }
#pragma unroll
    for (int mi = 0; mi < 4; ++mi)
#pragma unroll
      for (int ni = 0; ni < 4; ++ni)
        acc[mi][ni] = MFMA(av[mi], bv[ni], acc[mi][ni]);
#pragma unroll
    for (int mi = 0; mi < 4; ++mi)
      av[mi] = *(const f16x8*)&Ac[LIDX(wr * 64 + mi * 16 + llo, 4 + lhi)];
#pragma unroll
    for (int ni = 0; ni < 4; ++ni)
      bv[ni] = *(const f16x8*)&Bc[LIDX(wc * 64 + ni * 16 + llo, 4 + lhi)];
#pragma unroll
    for (int mi = 0; mi < 4; ++mi)
#pragma unroll
      for (int ni = 0; ni < 4; ++ni)
        acc[mi][ni] = MFMA(av[mi], bv[ni], acc[mi][ni]);
    __syncthreads();
  };
  kstep(As0, Bs0, As1, Bs1, 64);
  kstep(As1, Bs1, As0, Bs0, 128);
  kstep(As0, Bs0, As1, Bs1, 192);
  kstep(As1, Bs1, (f16*)nullptr, (f16*)nullptr, 0);

  unsigned long long sbits = 0ull;
#pragma unroll
  for (int mi = 0; mi < 4; ++mi)
#pragma unroll
    for (int ni = 0; ni < 4; ++ni)
#pragma unroll
      for (int r = 0; r < 4; ++r) {
        const int f  = fb + wr * 64 + mi * 16 + lhi * 4 + r;
        const int yx = yxb + wc * 64 + ni * 16 + llo;
        const int y = yx >> 6, x = yx & 63;
        const int t = (63 - (f >> 6) + y) * 127 + (63 - (f & 63) + x);
        const float4 tv = tbl[t];
        const float s  = acc[mi][ni][r];
        const float q  = 0.5f * tv.y;            // 0.5*vp
        const float qa = q * tv.z;               // 0.5*vp*a
        const float h1 = q - qa, h2 = q + qa;
        const float sg0 = (s > 0.f) ? 1.f : ((s < 0.f) ? -1.f : 0.f);
        const float act = h1 * fabsf(s) + h2 * s;
        const float dct = h1 * sg0 + h2;
        mres[((size_t)b * NFILT + f) * HWDIM + yx] = (f16)(dct * (act - tv.x));
        sbits |= (unsigned long long)(s > 0.f ? 1 : 0) << ((mi * 4 + ni) * 4 + r);
      }
  sgn[(((size_t)b * 32 + blockIdx.x) * 32 + blockIdx.y) * 256 + tid] = sbits;
}

// ---------- K2: fgrad_loss split-K partials ----------
// grid (64,2,8): fbl=x*64, cb=y*128, z=b*4+s. Tile 64f x 128c, K-slice 1024,
// BK=64 (16 steps), 2-phase dbuf.
__global__ __launch_bounds__(256) void k_floss(
    const f16* __restrict__ mres, const f16* __restrict__ featc,
    f16* __restrict__ fpart)
{
  __shared__ f16 As0[64 * 64], As1[64 * 64], Bs0[128 * 64], Bs1[128 * 64];
  const int tid = threadIdx.x, w = tid >> 6, lane = tid & 63;
  const int llo = lane & 15, lhi = lane >> 4;
  const int bz = blockIdx.z, b = bz >> 2, s = bz & 3;
  const int fbl = blockIdx.x * 64, cb = blockIdx.y * 128;
  const int k0 = s * 1024;
  const f16* A  = mres  + ((size_t)b * NFILT + fbl) * HWDIM;
  const f16* Bg = featc + ((size_t)b * CDIM + cb) * HWDIM;

  f32x4 acc[4][2] = {};
  STAGE(A,  HWDIM, k0, As0, 64);
  STAGE(Bg, HWDIM, k0, Bs0, 128);
  __syncthreads();

  auto kstep = [&](const f16* Ac, const f16* Bc, f16* An, f16* Bn, int coln) {
    f16x8 av[4], bv[2];
#pragma unroll
    for (int mi = 0; mi < 4; ++mi)
      av[mi] = *(const f16x8*)&Ac[LIDX(mi * 16 + llo, lhi)];
#pragma unroll
    for (int ni = 0; ni < 2; ++ni)
      bv[ni] = *(const f16x8*)&Bc[LIDX(w * 32 + ni * 16 + llo, lhi)];
    if (An) { STAGE(A, HWDIM, coln, An, 64); STAGE(Bg, HWDIM, coln, Bn, 128); }
#pragma unroll
    for (int mi = 0; mi < 4; ++mi)
#pragma unroll
      for (int ni = 0; ni < 2; ++ni)
        acc[mi][ni] = MFMA(av[mi], bv[ni], acc[mi][ni]);
#pragma unroll
    for (int mi = 0; mi < 4; ++mi)
      av[mi] = *(const f16x8*)&Ac[LIDX(mi * 16 + llo, 4 + lhi)];
#pragma unroll
    for (int ni = 0; ni < 2; ++ni)
      bv[ni] = *(const f16x8*)&Bc[LIDX(w * 32 + ni * 16 + llo, 4 + lhi)];
#pragma unroll
    for (int mi = 0; mi < 4; ++mi)
#pragma unroll
      for (int ni = 0; ni < 2; ++ni)
        acc[mi][ni] = MFMA(av[mi], bv[ni], acc[mi][ni]);
    __syncthreads();
  };
#pragma unroll
  for (int ks = 0; ks < 16; ++ks) {
    const bool odd = ks & 1;
    kstep(odd ? As1 : As0, odd ? Bs1 : Bs0,
          ks < 15 ? (odd ? As0 : As1) : (f16*)nullptr,
          ks < 15 ? (odd ? Bs0 : Bs1) : (f16*)nullptr,
          k0 + (ks + 1) * 64);
  }

#pragma unroll
  for (int mi = 0; mi < 4; ++mi)
#pragma unroll
    for (int ni = 0; ni < 2; ++ni)
#pragma unroll
      for (int r = 0; r < 4; ++r) {
        const int f = fbl + mi * 16 + lhi * 4 + r;
        const int c = cb + w * 32 + ni * 16 + llo;
        fpart[(((size_t)b * 4 + s) * NFILT + f) * CDIM + c] = (f16)acc[mi][ni][r];
      }
}

// ---------- K2b: fgrad = rw*filt + sum(partials); alpha_num ----------
// grid (1024,2): wave w owns f = x*4+w, b = y; lane covers 4 c.
__global__ __launch_bounds__(256) void k_fgrad(
    const f16* __restrict__ fpart, const float* __restrict__ filt32,
    const float* __restrict__ freg,
    float* __restrict__ fgrad32, f16* __restrict__ fgrad16,
    float* __restrict__ anum)
{
  const int tid = threadIdx.x, w = tid >> 6, lane = tid & 63;
  const int f = blockIdx.x * 4 + w, b = blockIdx.y;
  const float fr = freg[0];
  const float rw = fmaxf(fr * fr, 1e-10f);
  float4 sum = make_float4(0.f, 0.f, 0.f, 0.f);
#pragma unroll
  for (int s = 0; s < 4; ++s) {
    f16x4 p = *(const f16x4*)&fpart[(((size_t)b * 4 + s) * NFILT + f) * CDIM + lane * 4];
    sum.x += (float)p[0]; sum.y += (float)p[1];
    sum.z += (float)p[2]; sum.w += (float)p[3];
  }
  const size_t row4 = ((size_t)b * NFILT + f) * 64 + lane;
  const float4 fv = ((const float4*)filt32)[row4];
  float4 fg;
  fg.x = rw * fv.x + sum.x; fg.y = rw * fv.y + sum.y;
  fg.z = rw * fv.z + sum.z; fg.w = rw * fv.w + sum.w;
  ((float4*)fgrad32)[row4] = fg;
  f16x4 h; h[0] = (f16)fg.x; h[1] = (f16)fg.y; h[2] = (f16)fg.z; h[3] = (f16)fg.w;
  *(f16x4*)&fgrad16[row4 * 4] = h;
  float ss = fg.x * fg.x + fg.y * fg.y + fg.z * fg.z + fg.w * fg.w;
  ss += __shfl_xor(ss, 1);  ss += __shfl_xor(ss, 2);  ss += __shfl_xor(ss, 4);
  ss += __shfl_xor(ss, 8);  ss += __shfl_xor(ss, 16); ss += __shfl_xor(ss, 32);
  if (lane == 0) anum[b * NFILT + f] = ss;
}

// ---------- K3: sg GEMM + den_res^2 partials ----------
// grid (32,32,2) — same geometry as k_score; writes denp[2][64][4096].
__global__ __launch_bounds__(256) void k_sg(
    const f16* __restrict__ fgrad16, const f16* __restrict__ featT,
    const float4* __restrict__ tbl, const unsigned long long* __restrict__ sgn,
    float* __restrict__ denp)
{
  __shared__ f16 As0[128 * 64], As1[128 * 64], Bs0[128 * 64], Bs1[128 * 64];
  const int tid = threadIdx.x, w = tid >> 6, lane = tid & 63;
  const int llo = lane & 15, lhi = lane >> 4;
  const int wr = w >> 1, wc = w & 1;
  const int b = blockIdx.z;
  const int fb = blockIdx.x * 128, yxb = blockIdx.y * 128;
  const f16* A  = fgrad16 + ((size_t)b * NFILT + fb) * CDIM;
  const f16* Bg = featT   + ((size_t)b * HWDIM + yxb) * CDIM;

  f32x4 acc[4][4] = {};
  STAGE(A,  CDIM, 0, As0, 128);
  STAGE(Bg, CDIM, 0, Bs0, 128);
  __syncthreads();

  auto kstep = [&](const f16* Ac, const f16* Bc, f16* An, f16* Bn, int coln) {
    f16x8 av[4], bv[4];
#pragma unroll
    for (int mi = 0; mi < 4; ++mi)
      av[mi] = *(const f16x8*)&Ac[LIDX(wr * 64 + mi * 16 + llo, lhi)];
#pragma unroll
    for (int ni = 0; ni < 4; ++ni)
      bv[ni] = *(const f16x8*)&Bc[LIDX(wc * 64 + ni * 16 + llo, lhi)];
    if (An) { STAGE(A, CDIM, coln, An, 128); STAGE(Bg, CDIM, coln, Bn, 128); }
#pragma unroll
    for (int mi = 0; mi < 4; ++mi)
#pragma unroll
      for (int ni = 0; ni < 4; ++ni)
        acc[mi][ni] = MFMA(av[mi], bv[ni], acc[mi][ni]);
#pragma unroll
    for (int mi = 0; mi < 4; ++mi)
      av[mi] = *(const f16x8*)&Ac[LIDX(wr * 64 + mi * 16 + llo, 4 + lhi)];
#pragma unroll
    for (int ni = 0; ni < 4; ++ni)
      bv[ni] = *(const f16x8*)&Bc[LIDX(wc * 64 + ni * 16 + llo, 4 + lhi)];
#pragma unroll
    for (int mi = 0; mi < 4; ++mi)
#pragma unroll
      for (int ni = 0; ni < 4; ++ni)
        acc[mi][ni] = MFMA(av[mi], bv[ni], acc[mi][ni]);
    __syncthreads();
  };
  kstep(As0, Bs0, As1, Bs1, 64);
  kstep(As1, Bs1, As0, Bs0, 128);
  kstep(As0, Bs0, As1, Bs1, 192);
  kstep(As1, Bs1, (f16*)nullptr, (f16*)nullptr, 0);

  const unsigned long long sbits =
      sgn[(((size_t)b * 32 + blockIdx.x) * 32 + blockIdx.y) * 256 + tid];
  float dacc[4][4] = {};                               // [mi][r]
#pragma unroll
  for (int mi = 0; mi < 4; ++mi)
#pragma unroll
    for (int ni = 0; ni < 4; ++ni)
#pragma unroll
      for (int r = 0; r < 4; ++r) {
        const int f  = fb + wr * 64 + mi * 16 + lhi * 4 + r;
        const int yx = yxb + wc * 64 + ni * 16 + llo;
        const int y = yx >> 6, x = yx & 63;
        const int t = (63 - (f >> 6) + y) * 127 + (63 - (f & 63) + x);
        const float4 tv = tbl[t];
        const float q  = 0.5f * tv.y;
        const float qa = q * tv.z;
        const float h1 = q - qa, h2 = q + qa;
        const float sg0 = ((sbits >> ((mi * 4 + ni) * 4 + r)) & 1ull) ? 1.f : -1.f;
        const float dct = h1 * sg0 + h2;
        const float dr  = dct * acc[mi][ni][r];
        dacc[mi][r] += dr * dr;
      }
#pragma unroll
  for (int mi = 0; mi < 4; ++mi)
#pragma unroll
    for (int r = 0; r < 4; ++r) {
      float v = dacc[mi][r];
      v += __shfl_xor(v, 1); v += __shfl_xor(v, 2);
      v += __shfl_xor(v, 4); v += __shfl_xor(v, 8);
      if (llo == 0)
        denp[((size_t)b * 64 + blockIdx.y * 2 + wc) * NFILT +
             fb + wr * 64 + mi * 16 + lhi * 4 + r] = v;
    }
}

// ---------- K4: alpha + filter update (master in d_out) ----------
// grid 2048, 256 thr; i covers [2][4096][64] float4s.
__global__ __launch_bounds__(256) void k_update(
    float* __restrict__ filt32, const float* __restrict__ fgrad32,
    const float* __restrict__ anum, const float* __restrict__ denp,
    const float* __restrict__ lsl, const float* __restrict__ freg,
    f16* __restrict__ filt16o)
{
  const int i = blockIdx.x * 256 + threadIdx.x;
  const int bf = i >> 6, cq = i & 63;
  const int b = bf >> 12, f = bf & (NFILT - 1);
  const float fr = freg[0];
  const float rw = fmaxf(fr * fr, 1e-10f);
  const float sl = expf(lsl[0]);
  float den = 0.f;
#pragma unroll
  for (int j = 0; j < 64; ++j) den += denp[((size_t)b * 64 + j) * NFILT + f];
  const float num = anum[bf];
  const float alpha = num / fmaxf(den + rw * num, 1e-8f);   // STEPLEN_REG = 0
  const float st = sl * alpha;
  const size_t row4 = (size_t)bf * 64 + cq;
  const float4 fv = ((const float4*)filt32)[row4];
  const float4 gv = ((const float4*)fgrad32)[row4];
  float4 nv;
  nv.x = fv.x - st * gv.x; nv.y = fv.y - st * gv.y;
  nv.z = fv.z - st * gv.z; nv.w = fv.w - st * gv.w;
  ((float4*)filt32)[row4] = nv;
  f16x4 h; h[0] = (f16)nv.x; h[1] = (f16)nv.y; h[2] = (f16)nv.z; h[3] = (f16)nv.w;
  *(f16x4*)&filt16o[row4 * 4] = h;
}

extern "C" void kernel_launch(void* const* d_in, const int* in_sizes, int n_in,
                              void* d_out, int out_size, void* d_ws, size_t ws_size,
                              hipStream_t stream) {
  (void)in_sizes; (void)n_in; (void)out_size; (void)ws_size;
  const float* filt  = (const float*)d_in[0];   // filter_map [2][4096][256]
  const float* rfeat = (const float*)d_in[1];   // reference_feat [1][2][256][64][64]
  const float* wl  = (const float*)d_in[3];
  const float* wsp = (const float*)d_in[4];
  const float* wmk = (const float*)d_in[5];
  const float* lsl = (const float*)d_in[6];
  const float* fre = (const float*)d_in[7];

  char* ws = (char*)d_ws;                             // ~110 MB of 256 MB
  float4* tbl    = (float4*)(ws + 0);                 // 258 KB (pad 256K)
  f16* featc     = (f16*)(ws + 262144);               // 4 MB [2][256][4096]
  f16* featT     = (f16*)(ws + 4456448);              // 4 MB [2][4096][256]
  f16* filt16    = (f16*)(ws + 8650752);              // 4 MB [2][4096][256]
  f16* fgrad16   = (f16*)(ws + 12845056);             // 4 MB [2][4096][256]
  float* fgrad32 = (float*)(ws + 17039360);           // 8 MB [2][4096][256]
  float* anum    = (float*)(ws + 25427968);           // 32 KB [2][4096]
  float* denp    = (float*)(ws + 25460736);           // 2 MB [2][64][4096]
  unsigned long long* sgn = (unsigned long long*)(ws + 27557888);  // 4 MB
  f16* mres      = (f16*)(ws + 31752192);             // 64 MB [2][4096][4096]
  f16* fpart     = (f16*)(ws + 98861056);             // 16 MB [2][4][4096][256]
  float* filt32  = (float*)d_out;                     // master f32 (8 MB)

  k_maps<<<64, 256, 0, stream>>>(wl, wsp, wmk, tbl);
  k_convert<<<512, 256, 0, stream>>>(rfeat, featc, featT);
  k_filt16<<<2048, 256, 0, stream>>>(filt, filt32, filt16);

  for (int it = 0; it < 2; ++it) {
    k_score<<<dim3(32, 32, 2), 256, 0, stream>>>(filt16, featT, tbl, mres, sgn);
    k_floss<<<dim3(64, 2, 8), 256, 0, stream>>>(mres, featc, fpart);
    k_fgrad<<<dim3(1024, 2), 256, 0, stream>>>(fpart, filt32, fre,
                                               fgrad32, fgrad16, anum);
    k_sg<<<dim3(32, 32, 2), 256, 0, stream>>>(fgrad16, featT, tbl, sgn, denp);
    k_update<<<2048, 256, 0, stream>>>(filt32, fgrad32, anum, denp, lsl, fre,
                                       filt16);
  }
}

// Round 9
// 370.396 us; speedup vs baseline: 2.5361x; 1.0241x over previous
//
#include <hip/hip_runtime.h>

// GlobalGOCorOpt for MI355X (gfx950) — round 9.
// Round-8 structure (13 launches, LDS GEMMs, 2-phase dbuf) +
//  (1) compressed epilogue math via precomputed {vl, pp=vp, pm=vp*wm} table,
//  (2) k_floss retiled 128x128 (grid 512 = zero dispatch tail),
//  (3) k_update denp wave-reduce.

#define NFILT 4096
#define CDIM  256
#define HWDIM 4096

typedef _Float16 f16;
typedef _Float16 f16x8 __attribute__((ext_vector_type(8)));
typedef _Float16 f16x4 __attribute__((ext_vector_type(4)));
typedef float f32x4 __attribute__((ext_vector_type(4)));

#define MFMA(a, b, c) __builtin_amdgcn_mfma_f32_16x16x32_f16((a), (b), (c), 0, 0, 0)

// Stage an [R rows x 64 f16] tile from g (row stride gstride f16, col offset
// col0) into linear LDS [R][64] via global_load_lds, global SOURCE pre-swizzled
// (slot ^= row&7) so XOR'd ds_reads are bank-balanced. Wave w covers rows
// [w*(R/4), +R/4); each inst stages 8 rows (64 lanes x 16B).
#define STAGE(g, gstride, col0, lds, R)                                         \
  {                                                                             \
    _Pragma("unroll")                                                           \
    for (int i_ = 0; i_ < (R) / 32; ++i_) {                                     \
      const int rbase_ = w * ((R) / 4) + i_ * 8;                                \
      const int row_   = rbase_ + (lane >> 3);                                  \
      const int slot_  = lane & 7;                                              \
      const int col_   = (col0) + ((slot_ ^ (row_ & 7)) << 3);                  \
      __builtin_amdgcn_global_load_lds(                                         \
          (const __attribute__((address_space(1))) void*)                       \
              ((g) + (size_t)row_ * (gstride) + col_),                          \
          (__attribute__((address_space(3))) void*)((lds) + rbase_ * 64),       \
          16, 0, 0);                                                            \
    }                                                                           \
  }

// XOR'd LDS read index for logical (row, 16B-slot)
#define LIDX(row, slot) (((row) * 64) + ((((slot) ^ ((row) & 7))) << 3))

// ---------- packed map table {vp*label, vp, vp*sigmoid(mask), 0} ----------
__global__ __launch_bounds__(256) void k_maps(
    const float* __restrict__ wl, const float* __restrict__ wsp,
    const float* __restrict__ wmk, float4* __restrict__ tbl)
{
  int i = blockIdx.x * 256 + threadIdx.x;
  if (i >= 127 * 127) return;
  int yy = i / 127, xx = i - yy * 127;
  float dy = (float)yy - 63.f, dx = (float)xx - 63.f;
  float d2 = 2.f * sqrtf(dy * dy + dx * dx);   // dist / BIN_DISP
  float l = 0.f, v = 0.f, m = 0.f;
#pragma unroll
  for (int k = 0; k < 9; ++k) {
    float t = fmaxf(1.f - fabsf(d2 - (float)k), 0.f);
    l += wl[k] * t; v += wsp[k] * t; m += wmk[k] * t;
  }
  float t9 = fminf(fmaxf(d2 - 8.f, 0.f), 1.f);
  l += wl[9] * t9; v += wsp[9] * t9; m += wmk[9] * t9;
  const float wm = 1.f / (1.f + expf(-m));
  tbl[i] = make_float4(v * l, v, v * wm, 0.f);
}

// ---------- feat f32 -> f16 [b][c][yx] and transposed [b][yx][c] ----------
__global__ __launch_bounds__(256) void k_convert(
    const float* __restrict__ feat, f16* __restrict__ featc,
    f16* __restrict__ featT)
{
  __shared__ float tbuf[64][65];
  int bid = blockIdx.x;                        // 512 blocks = 2b x 4cb x 64yb
  int b = bid >> 8, cb = (bid >> 6) & 3, yb = bid & 63;
  int ty = threadIdx.x & 63, tc = threadIdx.x >> 6;
  const float* src = feat + ((size_t)b * CDIM + cb * 64) * HWDIM + yb * 64;
#pragma unroll
  for (int s = 0; s < 16; ++s) {
    int c = s * 4 + tc;
    float v = src[(size_t)c * HWDIM + ty];
    tbuf[c][ty] = v;
    featc[((size_t)b * CDIM + cb * 64 + c) * HWDIM + yb * 64 + ty] = (f16)v;
  }
  __syncthreads();
#pragma unroll
  for (int s = 0; s < 16; ++s) {
    int y = s * 4 + tc;
    featT[((size_t)b * HWDIM + yb * 64 + y) * CDIM + cb * 64 + ty] = (f16)tbuf[ty][y];
  }
}

// ---------- filter_map f32 -> master f32 copy (in d_out) + f16 ----------
__global__ __launch_bounds__(256) void k_filt16(
    const float* __restrict__ src, float* __restrict__ dst32,
    f16* __restrict__ dst16)
{
  const int i = blockIdx.x * 256 + threadIdx.x;       // float4 index
  const float4 v = ((const float4*)src)[i];
  ((float4*)dst32)[i] = v;
  f16x4 h; h[0] = (f16)v.x; h[1] = (f16)v.y; h[2] = (f16)v.z; h[3] = (f16)v.w;
  *(f16x4*)&dst16[(size_t)i * 4] = h;
}

// ---------- K1: scores GEMM + mres epilogue ----------
// grid (32,32,2): fb=x*128, yxb=y*128, b=z. Tile 128f x 128yx, waves 2x2,
// BK=64, K=256, 2-phase dbuf.
__global__ __launch_bounds__(256) void k_score(
    const f16* __restrict__ filt16, const f16* __restrict__ featT,
    const float4* __restrict__ tbl, f16* __restrict__ mres,   // [2][4096][HW]
    unsigned long long* __restrict__ sgn)
{
  __shared__ f16 As0[128 * 64], As1[128 * 64], Bs0[128 * 64], Bs1[128 * 64];
  const int tid = threadIdx.x, w = tid >> 6, lane = tid & 63;
  const int llo = lane & 15, lhi = lane >> 4;
  const int wr = w >> 1, wc = w & 1;
  const int b = blockIdx.z;
  const int fb = blockIdx.x * 128, yxb = blockIdx.y * 128;
  const f16* A  = filt16 + ((size_t)b * NFILT + fb) * CDIM;
  const f16* Bg = featT  + ((size_t)b * HWDIM + yxb) * CDIM;

  f32x4 acc[4][4] = {};
  STAGE(A,  CDIM, 0, As0, 128);
  STAGE(Bg, CDIM, 0, Bs0, 128);
  __syncthreads();

  auto kstep = [&](const f16* Ac, const f16* Bc, f16* An, f16* Bn, int coln) {
    f16x8 av[4], bv[4];
#pragma unroll
    for (int mi = 0; mi < 4; ++mi)
      av[mi] = *(const f16x8*)&Ac[LIDX(wr * 64 + mi * 16 + llo, lhi)];
#pragma unroll
    for (int ni = 0; ni < 4; ++ni)
      bv[ni] = *(const f16x8*)&Bc[LIDX(wc * 64 + ni * 16 + llo, lhi)];
    if (An) { STAGE(A, CDIM, coln, An, 128); STAGE(Bg, CDIM, coln, Bn, 128); }
#pragma unroll
    for (int mi = 0; mi < 4; ++mi)
#pragma unroll
      for (int ni = 0; ni < 4; ++ni)
        acc[mi][ni] = MFMA(av[mi], bv[ni], acc[mi][ni]);
#pragma unroll
    for (int mi = 0; mi < 4; ++mi)
      av[mi] = *(const f16x8*)&Ac[LIDX(wr * 64 + mi * 16 + llo, 4 + lhi)];
#pragma unroll
    for (int ni = 0; ni < 4; ++ni)
      bv[ni] = *(const f16x8*)&Bc[LIDX(wc * 64 + ni * 16 + llo, 4 + lhi)];
#pragma unroll
    for (int mi = 0; mi < 4; ++mi)
#pragma unroll
      for (int ni = 0; ni < 4; ++ni)
        acc[mi][ni] = MFMA(av[mi], bv[ni], acc[mi][ni]);
    __syncthreads();
  };
  kstep(As0, Bs0, As1, Bs1, 64);
  kstep(As1, Bs1, As0, Bs0, 128);
  kstep(As0, Bs0, As1, Bs1, 192);
  kstep(As1, Bs1, (f16*)nullptr, (f16*)nullptr, 0);

  unsigned long long sbits = 0ull;
#pragma unroll
  for (int mi = 0; mi < 4; ++mi)
#pragma unroll
    for (int ni = 0; ni < 4; ++ni)
#pragma unroll
      for (int r = 0; r < 4; ++r) {
        const int f  = fb + wr * 64 + mi * 16 + lhi * 4 + r;
        const int yx = yxb + wc * 64 + ni * 16 + llo;
        const int y = yx >> 6, x = yx & 63;
        const int t = (63 - (f >> 6) + y) * 127 + (63 - (f & 63) + x);
        const float4 tv = tbl[t];                // {vl, pp, pm}
        const float s  = acc[mi][ni][r];
        const float sel = (s > 0.f) ? tv.y : tv.z;
        const float mr  = sel * fmaf(sel, s, -tv.x);
        mres[((size_t)b * NFILT + f) * HWDIM + yx] = (f16)mr;
        sbits |= (unsigned long long)(s > 0.f ? 1 : 0) << ((mi * 4 + ni) * 4 + r);
      }
  sgn[(((size_t)b * 32 + blockIdx.x) * 32 + blockIdx.y) * 256 + tid] = sbits;
}

// ---------- K2: fgrad_loss split-K partials ----------
// grid (32,2,8): fb=x*128, cb=y*128, z=b*4+s. Tile 128f x 128c, K-slice 1024,
// BK=64 (16 steps), 2-phase dbuf. 512 blocks = 2/CU exactly.
__global__ __launch_bounds__(256) void k_floss(
    const f16* __restrict__ mres, const f16* __restrict__ featc,
    f16* __restrict__ fpart)
{
  __shared__ f16 As0[128 * 64], As1[128 * 64], Bs0[128 * 64], Bs1[128 * 64];
  const int tid = threadIdx.x, w = tid >> 6, lane = tid & 63;
  const int llo = lane & 15, lhi = lane >> 4;
  const int wr = w >> 1, wc = w & 1;
  const int bz = blockIdx.z, b = bz >> 2, s = bz & 3;
  const int fb = blockIdx.x * 128, cb = blockIdx.y * 128;
  const int k0 = s * 1024;
  const f16* A  = mres  + ((size_t)b * NFILT + fb) * HWDIM;
  const f16* Bg = featc + ((size_t)b * CDIM + cb) * HWDIM;

  f32x4 acc[4][4] = {};
  STAGE(A,  HWDIM, k0, As0, 128);
  STAGE(Bg, HWDIM, k0, Bs0, 128);
  __syncthreads();

  auto kstep = [&](const f16* Ac, const f16* Bc, f16* An, f16* Bn, int coln) {
    f16x8 av[4], bv[4];
#pragma unroll
    for (int mi = 0; mi < 4; ++mi)
      av[mi] = *(const f16x8*)&Ac[LIDX(wr * 64 + mi * 16 + llo, lhi)];
#pragma unroll
    for (int ni = 0; ni < 4; ++ni)
      bv[ni] = *(const f16x8*)&Bc[LIDX(wc * 64 + ni * 16 + llo, lhi)];
    if (An) { STAGE(A, HWDIM, coln, An, 128); STAGE(Bg, HWDIM, coln, Bn, 128); }
#pragma unroll
    for (int mi = 0; mi < 4; ++mi)
#pragma unroll
      for (int ni = 0; ni < 4; ++ni)
        acc[mi][ni] = MFMA(av[mi], bv[ni], acc[mi][ni]);
#pragma unroll
    for (int mi = 0; mi < 4; ++mi)
      av[mi] = *(const f16x8*)&Ac[LIDX(wr * 64 + mi * 16 + llo, 4 + lhi)];
#pragma unroll
    for (int ni = 0; ni < 4; ++ni)
      bv[ni] = *(const f16x8*)&Bc[LIDX(wc * 64 + ni * 16 + llo, 4 + lhi)];
#pragma unroll
    for (int mi = 0; mi < 4; ++mi)
#pragma unroll
      for (int ni = 0; ni < 4; ++ni)
        acc[mi][ni] = MFMA(av[mi], bv[ni], acc[mi][ni]);
    __syncthreads();
  };
#pragma unroll
  for (int ks = 0; ks < 16; ++ks) {
    const bool odd = ks & 1;
    kstep(odd ? As1 : As0, odd ? Bs1 : Bs0,
          ks < 15 ? (odd ? As0 : As1) : (f16*)nullptr,
          ks < 15 ? (odd ? Bs0 : Bs1) : (f16*)nullptr,
          k0 + (ks + 1) * 64);
  }

#pragma unroll
  for (int mi = 0; mi < 4; ++mi)
#pragma unroll
    for (int ni = 0; ni < 4; ++ni)
#pragma unroll
      for (int r = 0; r < 4; ++r) {
        const int f = fb + wr * 64 + mi * 16 + lhi * 4 + r;
        const int c = cb + wc * 64 + ni * 16 + llo;
        fpart[(((size_t)b * 4 + s) * NFILT + f) * CDIM + c] = (f16)acc[mi][ni][r];
      }
}

// ---------- K2b: fgrad = rw*filt + sum(partials); alpha_num ----------
// grid (1024,2): wave w owns f = x*4+w, b = y; lane covers 4 c.
__global__ __launch_bounds__(256) void k_fgrad(
    const f16* __restrict__ fpart, const float* __restrict__ filt32,
    const float* __restrict__ freg,
    float* __restrict__ fgrad32, f16* __restrict__ fgrad16,
    float* __restrict__ anum)
{
  const int tid = threadIdx.x, w = tid >> 6, lane = tid & 63;
  const int f = blockIdx.x * 4 + w, b = blockIdx.y;
  const float fr = freg[0];
  const float rw = fmaxf(fr * fr, 1e-10f);
  float4 sum = make_float4(0.f, 0.f, 0.f, 0.f);
#pragma unroll
  for (int s = 0; s < 4; ++s) {
    f16x4 p = *(const f16x4*)&fpart[(((size_t)b * 4 + s) * NFILT + f) * CDIM + lane * 4];
    sum.x += (float)p[0]; sum.y += (float)p[1];
    sum.z += (float)p[2]; sum.w += (float)p[3];
  }
  const size_t row4 = ((size_t)b * NFILT + f) * 64 + lane;
  const float4 fv = ((const float4*)filt32)[row4];
  float4 fg;
  fg.x = rw * fv.x + sum.x; fg.y = rw * fv.y + sum.y;
  fg.z = rw * fv.z + sum.z; fg.w = rw * fv.w + sum.w;
  ((float4*)fgrad32)[row4] = fg;
  f16x4 h; h[0] = (f16)fg.x; h[1] = (f16)fg.y; h[2] = (f16)fg.z; h[3] = (f16)fg.w;
  *(f16x4*)&fgrad16[row4 * 4] = h;
  float ss = fg.x * fg.x + fg.y * fg.y + fg.z * fg.z + fg.w * fg.w;
  ss += __shfl_xor(ss, 1);  ss += __shfl_xor(ss, 2);  ss += __shfl_xor(ss, 4);
  ss += __shfl_xor(ss, 8);  ss += __shfl_xor(ss, 16); ss += __shfl_xor(ss, 32);
  if (lane == 0) anum[b * NFILT + f] = ss;
}

// ---------- K3: sg GEMM + den_res^2 partials ----------
// grid (32,32,2) — same geometry as k_score; writes denp[2][64][4096].
__global__ __launch_bounds__(256) void k_sg(
    const f16* __restrict__ fgrad16, const f16* __restrict__ featT,
    const float4* __restrict__ tbl, const unsigned long long* __restrict__ sgn,
    float* __restrict__ denp)
{
  __shared__ f16 As0[128 * 64], As1[128 * 64], Bs0[128 * 64], Bs1[128 * 64];
  const int tid = threadIdx.x, w = tid >> 6, lane = tid & 63;
  const int llo = lane & 15, lhi = lane >> 4;
  const int wr = w >> 1, wc = w & 1;
  const int b = blockIdx.z;
  const int fb = blockIdx.x * 128, yxb = blockIdx.y * 128;
  const f16* A  = fgrad16 + ((size_t)b * NFILT + fb) * CDIM;
  const f16* Bg = featT   + ((size_t)b * HWDIM + yxb) * CDIM;

  f32x4 acc[4][4] = {};
  STAGE(A,  CDIM, 0, As0, 128);
  STAGE(Bg, CDIM, 0, Bs0, 128);
  __syncthreads();

  auto kstep = [&](const f16* Ac, const f16* Bc, f16* An, f16* Bn, int coln) {
    f16x8 av[4], bv[4];
#pragma unroll
    for (int mi = 0; mi < 4; ++mi)
      av[mi] = *(const f16x8*)&Ac[LIDX(wr * 64 + mi * 16 + llo, lhi)];
#pragma unroll
    for (int ni = 0; ni < 4; ++ni)
      bv[ni] = *(const f16x8*)&Bc[LIDX(wc * 64 + ni * 16 + llo, lhi)];
    if (An) { STAGE(A, CDIM, coln, An, 128); STAGE(Bg, CDIM, coln, Bn, 128); }
#pragma unroll
    for (int mi = 0; mi < 4; ++mi)
#pragma unroll
      for (int ni = 0; ni < 4; ++ni)
        acc[mi][ni] = MFMA(av[mi], bv[ni], acc[mi][ni]);
#pragma unroll
    for (int mi = 0; mi < 4; ++mi)
      av[mi] = *(const f16x8*)&Ac[LIDX(wr * 64 + mi * 16 + llo, 4 + lhi)];
#pragma unroll
    for (int ni = 0; ni < 4; ++ni)
      bv[ni] = *(const f16x8*)&Bc[LIDX(wc * 64 + ni * 16 + llo, 4 + lhi)];
#pragma unroll
    for (int mi = 0; mi < 4; ++mi)
#pragma unroll
      for (int ni = 0; ni < 4; ++ni)
        acc[mi][ni] = MFMA(av[mi], bv[ni], acc[mi][ni]);
    __syncthreads();
  };
  kstep(As0, Bs0, As1, Bs1, 64);
  kstep(As1, Bs1, As0, Bs0, 128);
  kstep(As0, Bs0, As1, Bs1, 192);
  kstep(As1, Bs1, (f16*)nullptr, (f16*)nullptr, 0);

  const unsigned long long sbits =
      sgn[(((size_t)b * 32 + blockIdx.x) * 32 + blockIdx.y) * 256 + tid];
  float dacc[4][4] = {};                               // [mi][r]
#pragma unroll
  for (int mi = 0; mi < 4; ++mi)
#pragma unroll
    for (int ni = 0; ni < 4; ++ni)
#pragma unroll
      for (int r = 0; r < 4; ++r) {
        const int f  = fb + wr * 64 + mi * 16 + lhi * 4 + r;
        const int yx = yxb + wc * 64 + ni * 16 + llo;
        const int y = yx >> 6, x = yx & 63;
        const int t = (63 - (f >> 6) + y) * 127 + (63 - (f & 63) + x);
        const float4 tv = tbl[t];                      // {vl, pp, pm}
        const float dct = ((sbits >> ((mi * 4 + ni) * 4 + r)) & 1ull) ? tv.y : tv.z;
        const float dr  = dct * acc[mi][ni][r];
        dacc[mi][r] = fmaf(dr, dr, dacc[mi][r]);
      }
#pragma unroll
  for (int mi = 0; mi < 4; ++mi)
#pragma unroll
    for (int r = 0; r < 4; ++r) {
      float v = dacc[mi][r];
      v += __shfl_xor(v, 1); v += __shfl_xor(v, 2);
      v += __shfl_xor(v, 4); v += __shfl_xor(v, 8);
      if (llo == 0)
        denp[((size_t)b * 64 + blockIdx.y * 2 + wc) * NFILT +
             fb + wr * 64 + mi * 16 + lhi * 4 + r] = v;
    }
}

// ---------- K4: alpha + filter update (master in d_out) ----------
// grid 2048, 256 thr; wave owns one (b,f); lane = c-quad; den via wave-reduce.
__global__ __launch_bounds__(256) void k_update(
    float* __restrict__ filt32, const float* __restrict__ fgrad32,
    const float* __restrict__ anum, const float* __restrict__ denp,
    const float* __restrict__ lsl, const float* __restrict__ freg,
    f16* __restrict__ filt16o)
{
  const int i = blockIdx.x * 256 + threadIdx.x;
  const int bf = i >> 6, lane = threadIdx.x & 63;
  const int b = bf >> 12, f = bf & (NFILT - 1);
  const float fr = freg[0];
  const float rw = fmaxf(fr * fr, 1e-10f);
  const float sl = expf(lsl[0]);
  float den = denp[((size_t)b * 64 + lane) * NFILT + f];
  den += __shfl_xor(den, 1);  den += __shfl_xor(den, 2);
  den += __shfl_xor(den, 4);  den += __shfl_xor(den, 8);
  den += __shfl_xor(den, 16); den += __shfl_xor(den, 32);
  const float num = anum[bf];
  const float alpha = num / fmaxf(den + rw * num, 1e-8f);   // STEPLEN_REG = 0
  const float st = sl * alpha;
  const size_t row4 = (size_t)bf * 64 + lane;
  const float4 fv = ((const float4*)filt32)[row4];
  const float4 gv = ((const float4*)fgrad32)[row4];
  float4 nv;
  nv.x = fv.x - st * gv.x; nv.y = fv.y - st * gv.y;
  nv.z = fv.z - st * gv.z; nv.w = fv.w - st * gv.w;
  ((float4*)filt32)[row4] = nv;
  f16x4 h; h[0] = (f16)nv.x; h[1] = (f16)nv.y; h[2] = (f16)nv.z; h[3] = (f16)nv.w;
  *(f16x4*)&filt16o[row4 * 4] = h;
}

extern "C" void kernel_launch(void* const* d_in, const int* in_sizes, int n_in,
                              void* d_out, int out_size, void* d_ws, size_t ws_size,
                              hipStream_t stream) {
  (void)in_sizes; (void)n_in; (void)out_size; (void)ws_size;
  const float* filt  = (const float*)d_in[0];   // filter_map [2][4096][256]
  const float* rfeat = (const float*)d_in[1];   // reference_feat [1][2][256][64][64]
  const float* wl  = (const float*)d_in[3];
  const float* wsp = (const float*)d_in[4];
  const float* wmk = (const float*)d_in[5];
  const float* lsl = (const float*)d_in[6];
  const float* fre = (const float*)d_in[7];

  char* ws = (char*)d_ws;                             // ~110 MB of 256 MB
  float4* tbl    = (float4*)(ws + 0);                 // 258 KB (pad 256K)
  f16* featc     = (f16*)(ws + 262144);               // 4 MB [2][256][4096]
  f16* featT     = (f16*)(ws + 4456448);              // 4 MB [2][4096][256]
  f16* filt16    = (f16*)(ws + 8650752);              // 4 MB [2][4096][256]
  f16* fgrad16   = (f16*)(ws + 12845056);             // 4 MB [2][4096][256]
  float* fgrad32 = (float*)(ws + 17039360);           // 8 MB [2][4096][256]
  float* anum    = (float*)(ws + 25427968);           // 32 KB [2][4096]
  float* denp    = (float*)(ws + 25460736);           // 2 MB [2][64][4096]
  unsigned long long* sgn = (unsigned long long*)(ws + 27557888);  // 4 MB
  f16* mres      = (f16*)(ws + 31752192);             // 64 MB [2][4096][4096]
  f16* fpart     = (f16*)(ws + 98861056);             // 16 MB [2][4][4096][256]
  float* filt32  = (float*)d_out;                     // master f32 (8 MB)

  k_maps<<<64, 256, 0, stream>>>(wl, wsp, wmk, tbl);
  k_convert<<<512, 256, 0, stream>>>(rfeat, featc, featT);
  k_filt16<<<2048, 256, 0, stream>>>(filt, filt32, filt16);

  for (int it = 0; it < 2; ++it) {
    k_score<<<dim3(32, 32, 2), 256, 0, stream>>>(filt16, featT, tbl, mres, sgn);
    k_floss<<<dim3(32, 2, 8), 256, 0, stream>>>(mres, featc, fpart);
    k_fgrad<<<dim3(1024, 2), 256, 0, stream>>>(fpart, filt32, fre,
                                               fgrad32, fgrad16, anum);
    k_sg<<<dim3(32, 32, 2), 256, 0, stream>>>(fgrad16, featT, tbl, sgn, denp);
    k_update<<<2048, 256, 0, stream>>>(filt32, fgrad32, anum, denp, lsl, fre,
                                       filt16);
  }
}